// Round 2
// baseline (337.368 us; speedup 1.0000x reference)
//
#include <hip/hip_runtime.h>

// MaskedConv2D bf16-MFMA implicit GEMM, v5. B=8, CIN=COUT=64, H=W=256, K=3, PAD=1.
// GEMM view: M=64 (co), K=576 (ci*9 taps), N=pixels.
// Block: 512 thr = 8 waves; tile = 64 co x (4 rows x 64 cols).
// Wave v: output row (v&3), col-half (v>>2) -> wave tile 64co x 32px, acc 4x2 frags.
// mfma_f32_16x16x32_bf16: A[m=lane&15][k=(lane>>4)*8+j], C/D: col=lane&15, row=(lane>>4)*4+reg.
//
// v5 change vs v4 (theory: occupancy-bound, not pipeline-depth-bound):
// ci split into 2 passes of 32 channels. LDS 57KB -> 31.7KB => 4 blocks/CU
// (32 waves, 100% cap) instead of 2 (50%). launch_bounds(512,8) forces
// VGPR<=64 so 8 waves/SIMD are actually resident. Staging keeps an explicit
// depth-2 register pipeline per pass; pass-1's first loads issue BEFORE the
// barrier so they fly during pass-0 compute of other waves.

#define B_    8
#define C_    64
#define H_    256
#define W_    256
#define HW_   (H_ * W_)

typedef __attribute__((ext_vector_type(8))) short bf16x8;
typedef __attribute__((ext_vector_type(4))) float f32x4;

__device__ __forceinline__ unsigned short f2bf(float f) {
    unsigned int u = __float_as_uint(f);
    u = (u + 0x7FFFu + ((u >> 16) & 1u)) >> 16;   // RNE
    return (unsigned short)u;
}

// ---- weight conversion: fp32 [co][ci][3][3] -> bf16 A-fragment blob ----
// frag f = s*4 + mf  (s = tap*2 + kblk); lane l holds 8 bf16 at (f*64+l)*16 B:
//   co = mf*16 + (l&15); ci = kblk*32 + (l>>4)*8 + j
__global__ __launch_bounds__(256) void wconv(const float* __restrict__ wgt,
                                             unsigned short* __restrict__ wsA)
{
    const int gid  = blockIdx.x * 256 + threadIdx.x;   // 18*256 = 4608
    const int s    = gid >> 8;
    const int rest = gid & 255;
    const int mf   = rest >> 6;
    const int lane = rest & 63;
    const int tap  = s >> 1;
    const int kblk = s & 1;
    const int kh = tap / 3, kw = tap % 3;
    const int co = mf * 16 + (lane & 15);
    unsigned short v[8];
#pragma unroll
    for (int j = 0; j < 8; ++j) {
        const int ci = kblk * 32 + (lane >> 4) * 8 + j;
        v[j] = f2bf(wgt[((co * C_ + ci) * 3 + kh) * 3 + kw]);
    }
    unsigned short* dst = wsA + (size_t)gid * 8;
    *(uint4*)dst = *(const uint4*)v;
}

// ---- main kernel ----
#define TROWS 6          // 4 + 2 halo
#define TCOLS 66         // 64 + 2 halo
#define CELLP 40         // shorts per 32-ci half-cell (80 B, b128-aligned)
#define NU2   (TROWS * TCOLS * 4)   // 1584 staging units per pass
#define NTAIL (NU2 - 3 * 512)       // 48

__global__ __launch_bounds__(512, 8) void masked_conv_mfma(
    const float* __restrict__ x,
    const float* __restrict__ mask,
    const unsigned short* __restrict__ wsA,
    const float* __restrict__ bias,
    float* __restrict__ out)
{
    __shared__ __align__(16) unsigned short xs[TROWS * TCOLS * CELLP];  // 31680 B

    const int tid  = threadIdx.x;
    const int wave = tid >> 6;
    const int lane = tid & 63;
    const int l15  = lane & 15;
    const int lq   = lane >> 4;

    const int w0 = blockIdx.x * 64;
    const int h0 = blockIdx.y * 4;
    const int b  = blockIdx.z;

    const float* xb = x + (size_t)b * C_ * HW_;

    const int hrow = wave & 3;        // output row within tile
    const int nh   = wave >> 2;       // col half (0/1)
    const int h    = h0 + hrow;
    const int pcol = w0 + nh * 32 + (lane & 31);

    // ---- validity: branchless, loads issue early (overlap staging). Lanes
    // 0..31 cover the wave's 32 px (lanes 32..63 duplicate).
    int valid = 0;
    {
        const float* mb = mask + (size_t)b * HW_;
#pragma unroll
        for (int dh = -1; dh <= 1; ++dh) {
#pragma unroll
            for (int dw = -1; dw <= 1; ++dw) {
                const int hh = h + dh;
                const int ww = pcol + dw;
                const int ok = (hh >= 0) & (hh < H_) & (ww >= 0) & (ww < W_);
                const float mv = mb[ok ? (hh * W_ + ww) : 0];
                valid |= ok & (mv != 0.0f ? 1 : 0);
            }
        }
    }
    const int vn0 = __builtin_amdgcn_ds_bpermute(l15 << 2, valid);
    const int vn1 = __builtin_amdgcn_ds_bpermute((16 + l15) << 2, valid);

    f32x4 acc[4][2];
#pragma unroll
    for (int mf = 0; mf < 4; ++mf)
#pragma unroll
        for (int nf = 0; nf < 2; ++nf)
            acc[mf][nf] = (f32x4){0.f, 0.f, 0.f, 0.f};

    const bf16x8* wA = (const bf16x8*)wsA;

#pragma unroll 1
    for (int p = 0; p < 2; ++p) {
        // ---- stage x half-tile: [6 rows][66 cols][32 ci] bf16, depth-2 pipeline.
        // Unit u = (row, ci-octet oct2 in 0..3, col): 8 strided global dwords
        // -> 1 ds_write_b128. Lanes vary col => coalesced.
        float va0[8], va1[8];
        int   cl0, cl1, ok0, ok1;

        auto issue = [&](int k, float (&va)[8], int& cl, int& ok) {
            const int u   = tid + (k << 9);
            const int col = u % TCOLS;
            const int t2  = u / TCOLS;
            const int oct2 = t2 & 3;
            const int row  = t2 >> 2;
            const int gh = h0 - 1 + row;
            const int gw = w0 - 1 + col;
            ok = (gh >= 0) & (gh < H_) & (gw >= 0) & (gw < W_);
            const float* px = xb + ((size_t)((p * 4 + oct2) * 8) * H_
                                    + (ok ? gh : 0)) * W_ + (ok ? gw : 0);
#pragma unroll
            for (int j = 0; j < 8; ++j) va[j] = px[(size_t)j * HW_];
            cl = (row * TCOLS + col) * CELLP + oct2 * 8;
        };
        auto wr = [&](const float (&va)[8], int cl, int ok) {
            unsigned short v[8];
#pragma unroll
            for (int j = 0; j < 8; ++j)
                v[j] = ok ? f2bf(va[j]) : (unsigned short)0;
            *(uint4*)&xs[cl] = *(const uint4*)v;
        };

        issue(0, va0, cl0, ok0);
        issue(1, va1, cl1, ok1);
        if (p) __syncthreads();            // protect xs from pass-0 readers
        wr(va0, cl0, ok0);
        issue(2, va0, cl0, ok0);
        wr(va1, cl1, ok1);
        if (tid < NTAIL) issue(3, va1, cl1, ok1);
        wr(va0, cl0, ok0);
        if (tid < NTAIL) wr(va1, cl1, ok1);
        __syncthreads();

        // ---- K loop: 9 taps, 32-ci half per pass, no barriers ----
#pragma unroll 1
        for (int kh = 0; kh < 3; ++kh) {
            const int rowbase = (hrow + kh) * TCOLS + nh * 32;
#pragma unroll
            for (int kw = 0; kw < 3; ++kw) {
                const int s = (kh * 3 + kw) * 2 + p;
                bf16x8 a[4];
#pragma unroll
                for (int mf = 0; mf < 4; ++mf)
                    a[mf] = wA[(s * 4 + mf) * 64 + lane];
                bf16x8 bfv[2];
#pragma unroll
                for (int nf = 0; nf < 2; ++nf) {
                    const int cell2 = rowbase + nf * 16 + l15 + kw;
                    bfv[nf] = *(const bf16x8*)&xs[cell2 * CELLP + lq * 8];
                }
#pragma unroll
                for (int mf = 0; mf < 4; ++mf)
#pragma unroll
                    for (int nf = 0; nf < 2; ++nf)
                        acc[mf][nf] = __builtin_amdgcn_mfma_f32_16x16x32_bf16(
                            a[mf], bfv[nf], acc[mf][nf], 0, 0, 0);
            }
        }
    }

    // ---- epilogue: bias + mask select + store ----
#pragma unroll
    for (int nf = 0; nf < 2; ++nf) {
        const int cloc = nf * 16 + l15;                       // 0..31 within half
        const int vn = nf ? vn1 : vn0;
        float* ob = out + ((size_t)(b * C_) * H_ + h) * W_ + w0 + nh * 32 + cloc;
#pragma unroll
        for (int mf = 0; mf < 4; ++mf) {
#pragma unroll
            for (int reg = 0; reg < 4; ++reg) {
                const int co = mf * 16 + lq * 4 + reg;
                const float val = vn ? (acc[mf][nf][reg] + bias[co]) : 0.0f;
                ob[(size_t)co * HW_] = val;
            }
        }
    }
}

extern "C" void kernel_launch(void* const* d_in, const int* in_sizes, int n_in,
                              void* d_out, int out_size, void* d_ws, size_t ws_size,
                              hipStream_t stream) {
    const float* x    = (const float*)d_in[0];
    const float* mask = (const float*)d_in[1];
    const float* wgt  = (const float*)d_in[2];
    const float* bias = (const float*)d_in[3];
    float* out        = (float*)d_out;
    unsigned short* wsA = (unsigned short*)d_ws;   // 73728 B used

    wconv<<<18, 256, 0, stream>>>(wgt, wsA);

    dim3 grid(W_ / 64, H_ / 4, B_);
    masked_conv_mfma<<<grid, 512, 0, stream>>>(x, mask, wsA, bias, out);
}

// Round 3
// 336.936 us; speedup vs baseline: 1.0013x; 1.0013x over previous
//
#include <hip/hip_runtime.h>

// MaskedConv2D bf16-MFMA implicit GEMM, v6. B=8, CIN=COUT=64, H=W=256, K=3, PAD=1.
// GEMM view: M=64 (co), K=576 (ci*9 taps), N=pixels.
// Block: 512 thr = 8 waves; tile = 64 co x (4 rows x 64 cols).
// Wave v: output row (v&3), col-half (v>>2) -> wave tile 64co x 32px, acc 4x2 frags.
// mfma_f32_16x16x32_bf16: A[m=lane&15][k=(lane>>4)*8+j], C/D: col=lane&15, row=(lane>>4)*4+reg.
//
// v6 vs v4/v5 (post-mortem: v5's launch_bounds(512,8) spilled acc -> +220MB
// scratch traffic; occupancy lever itself was confirmed, HBM rose 2.7->3.25).
// This version gets 3 blocks/CU WITHOUT register pressure:
//  - CELLP 72 -> 64 (no pad): LDS 57024 -> 50688 B => 3 blocks/CU (75% wave cap).
//  - Unpadded 128B cell stride would be a 32-way bank conflict on ds_read_b128,
//    so the 16B ci-octet group is XOR-swizzled: octet g of cell c lives at
//    xs[c*64 + ((g ^ (c&7))<<3)]. Same involution on write and read; 16B
//    alignment preserved; reads spread across 8 even bank-starts (v4-level).
//  - launch_bounds(512,6): VGPR cap 85 (acc=32 fits, headroom for pipelining).

#define B_    8
#define C_    64
#define H_    256
#define W_    256
#define HW_   (H_ * W_)

typedef __attribute__((ext_vector_type(8))) short bf16x8;
typedef __attribute__((ext_vector_type(4))) float f32x4;

__device__ __forceinline__ unsigned short f2bf(float f) {
    unsigned int u = __float_as_uint(f);
    u = (u + 0x7FFFu + ((u >> 16) & 1u)) >> 16;   // RNE
    return (unsigned short)u;
}

// ---- weight conversion: fp32 [co][ci][3][3] -> bf16 A-fragment blob ----
// frag f = s*4 + mf  (s = tap*2 + kblk); lane l holds 8 bf16 at (f*64+l)*16 B:
//   co = mf*16 + (l&15); ci = kblk*32 + (l>>4)*8 + j
__global__ __launch_bounds__(256) void wconv(const float* __restrict__ wgt,
                                             unsigned short* __restrict__ wsA)
{
    const int gid  = blockIdx.x * 256 + threadIdx.x;   // 18*256 = 4608
    const int s    = gid >> 8;
    const int rest = gid & 255;
    const int mf   = rest >> 6;
    const int lane = rest & 63;
    const int tap  = s >> 1;
    const int kblk = s & 1;
    const int kh = tap / 3, kw = tap % 3;
    const int co = mf * 16 + (lane & 15);
    unsigned short v[8];
#pragma unroll
    for (int j = 0; j < 8; ++j) {
        const int ci = kblk * 32 + (lane >> 4) * 8 + j;
        v[j] = f2bf(wgt[((co * C_ + ci) * 3 + kh) * 3 + kw]);
    }
    unsigned short* dst = wsA + (size_t)gid * 8;
    *(uint4*)dst = *(const uint4*)v;
}

// ---- main kernel ----
#define TROWS 6          // 4 + 2 halo
#define TCOLS 66         // 64 + 2 halo
#define NU    (TROWS * TCOLS * 8)   // 3168 staging units
#define NCHUNK 7                    // ceil(3168/512)

__global__ __launch_bounds__(512, 6) void masked_conv_mfma(
    const float* __restrict__ x,
    const float* __restrict__ mask,
    const unsigned short* __restrict__ wsA,
    const float* __restrict__ bias,
    float* __restrict__ out)
{
    // [cell = row*66+col][8 ci-octets, XOR-swizzled], 16B units. 50688 B.
    __shared__ __align__(16) unsigned short xs[TROWS * TCOLS * 64];

    const int tid  = threadIdx.x;
    const int wave = tid >> 6;
    const int lane = tid & 63;
    const int l15  = lane & 15;
    const int lq   = lane >> 4;

    const int w0 = blockIdx.x * 64;
    const int h0 = blockIdx.y * 4;
    const int b  = blockIdx.z;

    const float* xb = x + (size_t)b * C_ * HW_;

    const int hrow = wave & 3;        // output row within tile
    const int nh   = wave >> 2;       // col half (0/1)
    const int h    = h0 + hrow;
    const int pcol = w0 + nh * 32 + (lane & 31);

    // ---- validity: branchless, loads issue early (overlap staging). Lanes
    // 0..31 cover the wave's 32 px (lanes 32..63 duplicate).
    int valid = 0;
    {
        const float* mb = mask + (size_t)b * HW_;
#pragma unroll
        for (int dh = -1; dh <= 1; ++dh) {
#pragma unroll
            for (int dw = -1; dw <= 1; ++dw) {
                const int hh = h + dh;
                const int ww = pcol + dw;
                const int ok = (hh >= 0) & (hh < H_) & (ww >= 0) & (ww < W_);
                const float mv = mb[ok ? (hh * W_ + ww) : 0];
                valid |= ok & (mv != 0.0f ? 1 : 0);
            }
        }
    }

    // ---- stage x tile: [6 rows][66 cols][64 ci] bf16 ----
    // Work unit = (row, ci-octet, col): 8 strided global dwords -> 1 ds_write_b128.
    // Phase A: issue loads with branchless clamped addresses so they pipeline.
    float va[NCHUNK][8];
    int   cell[NCHUNK];
    int   okf[NCHUNK];
#pragma unroll
    for (int k = 0; k < NCHUNK; ++k) {
        const int u0 = tid + (k << 9);
        const int u  = (u0 < NU) ? u0 : 0;        // clamp: dup unit 0, write guarded
        const int col = u % TCOLS;
        const int t2  = u / TCOLS;
        const int oct = t2 & 7;
        const int row = t2 >> 3;
        const int gh = h0 - 1 + row;
        const int gw = w0 - 1 + col;
        const int ok = (gh >= 0) & (gh < H_) & (gw >= 0) & (gw < W_);
        const float* px = xb + ((size_t)(oct * 8) * H_ + (ok ? gh : 0)) * W_
                             + (ok ? gw : 0);
#pragma unroll
        for (int j = 0; j < 8; ++j) va[k][j] = px[(size_t)j * HW_];
        const int c = row * TCOLS + col;
        cell[k] = (c << 6) + ((oct ^ (c & 7)) << 3);   // XOR-swizzled octet slot
        okf[k]  = ok;
    }
    // Phase B: convert + LDS write
#pragma unroll
    for (int k = 0; k < NCHUNK; ++k) {
        if (k == NCHUNK - 1 && tid >= (NU - (NCHUNK - 1) * 512)) continue; // tid>=96
        unsigned short v[8];
#pragma unroll
        for (int j = 0; j < 8; ++j)
            v[j] = okf[k] ? f2bf(va[k][j]) : (unsigned short)0;
        *(uint4*)&xs[cell[k]] = *(const uint4*)v;
    }

    __syncthreads();

    // ---- hoist epilogue latency: bias frags + validity bpermutes ----
    float bv[4][4];
#pragma unroll
    for (int mf = 0; mf < 4; ++mf)
#pragma unroll
        for (int reg = 0; reg < 4; ++reg)
            bv[mf][reg] = bias[mf * 16 + lq * 4 + reg];
    const int vn0 = __builtin_amdgcn_ds_bpermute(l15 << 2, valid);
    const int vn1 = __builtin_amdgcn_ds_bpermute((16 + l15) << 2, valid);

    // ---- K loop: 9 taps x 2 ci-halves, no barriers ----
    f32x4 acc[4][2];
#pragma unroll
    for (int mf = 0; mf < 4; ++mf)
#pragma unroll
        for (int nf = 0; nf < 2; ++nf)
            acc[mf][nf] = (f32x4){0.f, 0.f, 0.f, 0.f};

    const bf16x8* wA = (const bf16x8*)wsA;

#pragma unroll 1
    for (int kh = 0; kh < 3; ++kh) {
        const int rowbase = (hrow + kh) * TCOLS + nh * 32;
#pragma unroll
        for (int kw = 0; kw < 3; ++kw) {
#pragma unroll
            for (int kblk = 0; kblk < 2; ++kblk) {
                const int s = (kh * 3 + kw) * 2 + kblk;
                bf16x8 a[4];
#pragma unroll
                for (int mf = 0; mf < 4; ++mf)
                    a[mf] = wA[(s * 4 + mf) * 64 + lane];
                bf16x8 bfv[2];
#pragma unroll
                for (int nf = 0; nf < 2; ++nf) {
                    const int cell2 = rowbase + nf * 16 + l15 + kw;
                    const int g = kblk * 4 + lq;               // ci-octet group
                    bfv[nf] = *(const bf16x8*)
                        &xs[(cell2 << 6) + ((g ^ (cell2 & 7)) << 3)];
                }
#pragma unroll
                for (int mf = 0; mf < 4; ++mf)
#pragma unroll
                    for (int nf = 0; nf < 2; ++nf)
                        acc[mf][nf] = __builtin_amdgcn_mfma_f32_16x16x32_bf16(
                            a[mf], bfv[nf], acc[mf][nf], 0, 0, 0);
            }
        }
    }

    // ---- epilogue: pure stores ----
#pragma unroll
    for (int nf = 0; nf < 2; ++nf) {
        const int cloc = nf * 16 + l15;                       // 0..31 within half
        const int vn = nf ? vn1 : vn0;
        float* ob = out + ((size_t)(b * C_) * H_ + h) * W_ + w0 + nh * 32 + cloc;
#pragma unroll
        for (int mf = 0; mf < 4; ++mf) {
#pragma unroll
            for (int reg = 0; reg < 4; ++reg) {
                const float val = vn ? (acc[mf][nf][reg] + bv[mf][reg]) : 0.0f;
                ob[(size_t)(mf * 16 + lq * 4 + reg) * HW_] = val;
            }
        }
    }
}

extern "C" void kernel_launch(void* const* d_in, const int* in_sizes, int n_in,
                              void* d_out, int out_size, void* d_ws, size_t ws_size,
                              hipStream_t stream) {
    const float* x    = (const float*)d_in[0];
    const float* mask = (const float*)d_in[1];
    const float* wgt  = (const float*)d_in[2];
    const float* bias = (const float*)d_in[3];
    float* out        = (float*)d_out;
    unsigned short* wsA = (unsigned short*)d_ws;   // 73728 B used

    wconv<<<18, 256, 0, stream>>>(wgt, wsA);

    dim3 grid(W_ / 64, H_ / 4, B_);
    masked_conv_mfma<<<grid, 512, 0, stream>>>(x, mask, wsA, bias, out);
}

// Round 4
// 306.297 us; speedup vs baseline: 1.1014x; 1.1000x over previous
//
#include <hip/hip_runtime.h>

// MaskedConv2D bf16-MFMA implicit GEMM, v7. B=8, CIN=COUT=64, H=W=256, K=3, PAD=1.
// GEMM view: M=64 (co), K=576 (ci*9 taps), N=pixels.
// Block: 512 thr = 8 waves; tile = 64 co x (4 rows x 64 cols).
// Wave v: output row (v&3), col-half (v>>2) -> wave tile 64co x 32px, acc 4x2 frags.
// mfma_f32_16x16x32_bf16: A[m=lane&15][k=(lane>>4)*8+j], C/D: col=lane&15, row=(lane>>4)*4+reg.
//
// v7 vs v6 (post-mortem: launch_bounds(512,6) cut the unified reg budget to
// ~80; acc(32 AGPR)+arch no longer fit -> va[] spilled to scratch = +190MB
// HBM traffic, dur 167us). One-line fix: launch_bounds back to (512,4)
// (budget 128, v4-proven spill-free at VGPR=52+32acc=84). The second arg is
// an allocator guarantee, NOT a residency cap: with LDS=50688B (v6's
// unpadded+XOR-swizzled layout, bank conflicts 2.43M->74K) the HW still
// co-schedules 3 blocks/CU = 24 waves = 6/SIMD, which 84 total regs also
// permits. Both verified wins, no spill tax.

#define B_    8
#define C_    64
#define H_    256
#define W_    256
#define HW_   (H_ * W_)

typedef __attribute__((ext_vector_type(8))) short bf16x8;
typedef __attribute__((ext_vector_type(4))) float f32x4;

__device__ __forceinline__ unsigned short f2bf(float f) {
    unsigned int u = __float_as_uint(f);
    u = (u + 0x7FFFu + ((u >> 16) & 1u)) >> 16;   // RNE
    return (unsigned short)u;
}

// ---- weight conversion: fp32 [co][ci][3][3] -> bf16 A-fragment blob ----
// frag f = s*4 + mf  (s = tap*2 + kblk); lane l holds 8 bf16 at (f*64+l)*16 B:
//   co = mf*16 + (l&15); ci = kblk*32 + (l>>4)*8 + j
__global__ __launch_bounds__(256) void wconv(const float* __restrict__ wgt,
                                             unsigned short* __restrict__ wsA)
{
    const int gid  = blockIdx.x * 256 + threadIdx.x;   // 18*256 = 4608
    const int s    = gid >> 8;
    const int rest = gid & 255;
    const int mf   = rest >> 6;
    const int lane = rest & 63;
    const int tap  = s >> 1;
    const int kblk = s & 1;
    const int kh = tap / 3, kw = tap % 3;
    const int co = mf * 16 + (lane & 15);
    unsigned short v[8];
#pragma unroll
    for (int j = 0; j < 8; ++j) {
        const int ci = kblk * 32 + (lane >> 4) * 8 + j;
        v[j] = f2bf(wgt[((co * C_ + ci) * 3 + kh) * 3 + kw]);
    }
    unsigned short* dst = wsA + (size_t)gid * 8;
    *(uint4*)dst = *(const uint4*)v;
}

// ---- main kernel ----
#define TROWS 6          // 4 + 2 halo
#define TCOLS 66         // 64 + 2 halo
#define NU    (TROWS * TCOLS * 8)   // 3168 staging units
#define NCHUNK 7                    // ceil(3168/512)

__global__ __launch_bounds__(512, 4) void masked_conv_mfma(
    const float* __restrict__ x,
    const float* __restrict__ mask,
    const unsigned short* __restrict__ wsA,
    const float* __restrict__ bias,
    float* __restrict__ out)
{
    // [cell = row*66+col][8 ci-octets, XOR-swizzled], 16B units. 50688 B.
    __shared__ __align__(16) unsigned short xs[TROWS * TCOLS * 64];

    const int tid  = threadIdx.x;
    const int wave = tid >> 6;
    const int lane = tid & 63;
    const int l15  = lane & 15;
    const int lq   = lane >> 4;

    const int w0 = blockIdx.x * 64;
    const int h0 = blockIdx.y * 4;
    const int b  = blockIdx.z;

    const float* xb = x + (size_t)b * C_ * HW_;

    const int hrow = wave & 3;        // output row within tile
    const int nh   = wave >> 2;       // col half (0/1)
    const int h    = h0 + hrow;
    const int pcol = w0 + nh * 32 + (lane & 31);

    // ---- validity: branchless, loads issue early (overlap staging). Lanes
    // 0..31 cover the wave's 32 px (lanes 32..63 duplicate).
    int valid = 0;
    {
        const float* mb = mask + (size_t)b * HW_;
#pragma unroll
        for (int dh = -1; dh <= 1; ++dh) {
#pragma unroll
            for (int dw = -1; dw <= 1; ++dw) {
                const int hh = h + dh;
                const int ww = pcol + dw;
                const int ok = (hh >= 0) & (hh < H_) & (ww >= 0) & (ww < W_);
                const float mv = mb[ok ? (hh * W_ + ww) : 0];
                valid |= ok & (mv != 0.0f ? 1 : 0);
            }
        }
    }

    // ---- stage x tile: [6 rows][66 cols][64 ci] bf16 ----
    // Work unit = (row, ci-octet, col): 8 strided global dwords -> 1 ds_write_b128.
    // Phase A: issue loads with branchless clamped addresses so they pipeline.
    float va[NCHUNK][8];
    int   cell[NCHUNK];
    int   okf[NCHUNK];
#pragma unroll
    for (int k = 0; k < NCHUNK; ++k) {
        const int u0 = tid + (k << 9);
        const int u  = (u0 < NU) ? u0 : 0;        // clamp: dup unit 0, write guarded
        const int col = u % TCOLS;
        const int t2  = u / TCOLS;
        const int oct = t2 & 7;
        const int row = t2 >> 3;
        const int gh = h0 - 1 + row;
        const int gw = w0 - 1 + col;
        const int ok = (gh >= 0) & (gh < H_) & (gw >= 0) & (gw < W_);
        const float* px = xb + ((size_t)(oct * 8) * H_ + (ok ? gh : 0)) * W_
                             + (ok ? gw : 0);
#pragma unroll
        for (int j = 0; j < 8; ++j) va[k][j] = px[(size_t)j * HW_];
        const int c = row * TCOLS + col;
        cell[k] = (c << 6) + ((oct ^ (c & 7)) << 3);   // XOR-swizzled octet slot
        okf[k]  = ok;
    }
    // Phase B: convert + LDS write
#pragma unroll
    for (int k = 0; k < NCHUNK; ++k) {
        if (k == NCHUNK - 1 && tid >= (NU - (NCHUNK - 1) * 512)) continue; // tid>=96
        unsigned short v[8];
#pragma unroll
        for (int j = 0; j < 8; ++j)
            v[j] = okf[k] ? f2bf(va[k][j]) : (unsigned short)0;
        *(uint4*)&xs[cell[k]] = *(const uint4*)v;
    }

    __syncthreads();

    // ---- hoist epilogue latency: bias frags + validity bpermutes ----
    float bv[4][4];
#pragma unroll
    for (int mf = 0; mf < 4; ++mf)
#pragma unroll
        for (int reg = 0; reg < 4; ++reg)
            bv[mf][reg] = bias[mf * 16 + lq * 4 + reg];
    const int vn0 = __builtin_amdgcn_ds_bpermute(l15 << 2, valid);
    const int vn1 = __builtin_amdgcn_ds_bpermute((16 + l15) << 2, valid);

    // ---- K loop: 9 taps x 2 ci-halves, no barriers ----
    f32x4 acc[4][2];
#pragma unroll
    for (int mf = 0; mf < 4; ++mf)
#pragma unroll
        for (int nf = 0; nf < 2; ++nf)
            acc[mf][nf] = (f32x4){0.f, 0.f, 0.f, 0.f};

    const bf16x8* wA = (const bf16x8*)wsA;

#pragma unroll 1
    for (int kh = 0; kh < 3; ++kh) {
        const int rowbase = (hrow + kh) * TCOLS + nh * 32;
#pragma unroll
        for (int kw = 0; kw < 3; ++kw) {
#pragma unroll
            for (int kblk = 0; kblk < 2; ++kblk) {
                const int s = (kh * 3 + kw) * 2 + kblk;
                bf16x8 a[4];
#pragma unroll
                for (int mf = 0; mf < 4; ++mf)
                    a[mf] = wA[(s * 4 + mf) * 64 + lane];
                bf16x8 bfv[2];
#pragma unroll
                for (int nf = 0; nf < 2; ++nf) {
                    const int cell2 = rowbase + nf * 16 + l15 + kw;
                    const int g = kblk * 4 + lq;               // ci-octet group
                    bfv[nf] = *(const bf16x8*)
                        &xs[(cell2 << 6) + ((g ^ (cell2 & 7)) << 3)];
                }
#pragma unroll
                for (int mf = 0; mf < 4; ++mf)
#pragma unroll
                    for (int nf = 0; nf < 2; ++nf)
                        acc[mf][nf] = __builtin_amdgcn_mfma_f32_16x16x32_bf16(
                            a[mf], bfv[nf], acc[mf][nf], 0, 0, 0);
            }
        }
    }

    // ---- epilogue: pure stores ----
#pragma unroll
    for (int nf = 0; nf < 2; ++nf) {
        const int cloc = nf * 16 + l15;                       // 0..31 within half
        const int vn = nf ? vn1 : vn0;
        float* ob = out + ((size_t)(b * C_) * H_ + h) * W_ + w0 + nh * 32 + cloc;
#pragma unroll
        for (int mf = 0; mf < 4; ++mf) {
#pragma unroll
            for (int reg = 0; reg < 4; ++reg) {
                const float val = vn ? (acc[mf][nf][reg] + bv[mf][reg]) : 0.0f;
                ob[(size_t)(mf * 16 + lq * 4 + reg) * HW_] = val;
            }
        }
    }
}

extern "C" void kernel_launch(void* const* d_in, const int* in_sizes, int n_in,
                              void* d_out, int out_size, void* d_ws, size_t ws_size,
                              hipStream_t stream) {
    const float* x    = (const float*)d_in[0];
    const float* mask = (const float*)d_in[1];
    const float* wgt  = (const float*)d_in[2];
    const float* bias = (const float*)d_in[3];
    float* out        = (float*)d_out;
    unsigned short* wsA = (unsigned short*)d_ws;   // 73728 B used

    wconv<<<18, 256, 0, stream>>>(wgt, wsA);

    dim3 grid(W_ / 64, H_ / 4, B_);
    masked_conv_mfma<<<grid, 512, 0, stream>>>(x, mask, wsA, bias, out);
}